// Round 1
// 502.688 us; speedup vs baseline: 1.2111x; 1.2111x over previous
//
#include <hip/hip_runtime.h>
#include <hip/hip_bf16.h>

typedef __bf16 bf16;
typedef __bf16 bf16x4 __attribute__((ext_vector_type(4)));
typedef __bf16 bf16x8 __attribute__((ext_vector_type(8)));
typedef float f32x4 __attribute__((ext_vector_type(4)));

#define B_ 2
#define H_ 32
#define HKV_ 8
#define S_ 2048
#define D_ 128
#define QT 64
#define KT 64
#define KST 136   // K LDS row stride (elems): 272B/row, 16B-aligned chunks
#define VST 68    // V^T LDS row stride: 136B/row (8B-aligned rows -> b64 reads)
#define PST 72    // P LDS row stride: 144B/row, 16B-aligned
#define NEG_BIG (-1.0e30f)
#define SCL 0.12751745f  // (1/sqrt(128)) * log2(e): softmax in exp2 domain
#define DEFER_THR 8.0f   // T13: skip O-rescale while max grows < 2^8

__device__ __forceinline__ bf16x8 cvt8p(float4 a, float4 b) {
  bf16x8 r = {(bf16)a.x, (bf16)a.y, (bf16)a.z, (bf16)a.w,
              (bf16)b.x, (bf16)b.y, (bf16)b.z, (bf16)b.w};
  return r;
}
__device__ __forceinline__ bf16x8 cvt8(const float* f) {
  return cvt8p(*(const float4*)f, *(const float4*)(f + 4));
}

// MFMA causal GQA flash attention. f32 inputs (bf16 compute), f32 OUTPUT.
// One block = 64 q-rows of one (b,h); wave w owns q-rows [w*16, w*16+16).
// R1: async-STAGE split (T14): next K/V tile global loads issued at iter top
// into regs (raw f32), committed to LDS after the post-compute barrier.
__global__ __launch_bounds__(256, 3) void fa_mfma(
    const float* __restrict__ q, const float* __restrict__ k,
    const float* __restrict__ v, float* __restrict__ out) {
  __shared__ bf16 Ks[KT * KST];      // K tile [key][d]
  __shared__ bf16 Vt[D_ * VST];      // V tile transposed [d][key]
  __shared__ bf16 Ps[4 * 16 * PST];  // per-wave P [qrow][key]

  const int tid = threadIdx.x, wave = tid >> 6, lane = tid & 63;
  const int col = lane & 15, quad = lane >> 4;
  const int bid = blockIdx.x;
  const int tq = 31 - (bid & 31);  // diagonal-heavy tiles first
  const int bh = bid >> 5, b = bh >> 5, h = bh & 31, hkv = h >> 2;  // GQA h/4

  const float* qh = q + (size_t)(b * H_ + h) * S_ * D_;
  const float* kh = k + (size_t)(b * HKV_ + hkv) * S_ * D_;
  const float* vh = v + (size_t)(b * HKV_ + hkv) * S_ * D_;
  float* oh = out + (size_t)(b * H_ + h) * S_ * D_;
  const int q0 = tq * QT;

  // Q A-fragments: A[m=lane&15][k=quad*8+j], chunk ks covers d in [ks*32,ks*32+32)
  bf16x8 qf[4];
  {
    const float* qrow = qh + (size_t)(q0 + wave * 16 + col) * D_ + quad * 8;
#pragma unroll
    for (int ks = 0; ks < 4; ++ks) qf[ks] = cvt8(qrow + ks * 32);
  }

  f32x4 o[8];
#pragma unroll
  for (int i = 0; i < 8; ++i) o[i] = (f32x4){0.f, 0.f, 0.f, 0.f};
  float m_i[4], lp[4];  // lp: per-lane PARTIAL l (reduced across 16 lanes only
                        // in the epilogue; alpha is row-uniform so this is exact)
#pragma unroll
  for (int r = 0; r < 4; ++r) { m_i[r] = NEG_BIG; lp[r] = 0.f; }

  // staging geometry (same as before, hoisted)
  const int krow = tid >> 4, kcc = tid & 15;  // K: rows krow+16*i, 16B col kcc
  const int kb = (tid >> 4) * 4;              // V: 4 consecutive keys
  const int dofs = (tid & 15) * 8;            // V: 8 consecutive d

  float4 kpre[8], vpre[8];  // raw f32 prefetch (held across compute)

  auto issue = [&](int j) {  // issue global loads, no use -> no wait here
    const float* kbase = kh + (size_t)j * KT * D_;
    const float* vbase = vh + (size_t)j * KT * D_;
#pragma unroll
    for (int i = 0; i < 4; ++i) {
      const float* p = kbase + (size_t)(krow + 16 * i) * D_ + kcc * 8;
      kpre[2 * i] = *(const float4*)p;
      kpre[2 * i + 1] = *(const float4*)(p + 4);
    }
#pragma unroll
    for (int i = 0; i < 4; ++i) {
      const float* p = vbase + (size_t)(kb + i) * D_ + dofs;
      vpre[2 * i] = *(const float4*)p;
      vpre[2 * i + 1] = *(const float4*)(p + 4);
    }
  };

  auto commit = [&]() {  // f32->bf16 + LDS write (between barriers)
#pragma unroll
    for (int i = 0; i < 4; ++i)
      *(bf16x8*)&Ks[(krow + 16 * i) * KST + kcc * 8] =
          cvt8p(kpre[2 * i], kpre[2 * i + 1]);
    bf16x8 vv[4];
#pragma unroll
    for (int i = 0; i < 4; ++i) vv[i] = cvt8p(vpre[2 * i], vpre[2 * i + 1]);
#pragma unroll
    for (int jj = 0; jj < 8; ++jj) {
      bf16x4 pk = {vv[0][jj], vv[1][jj], vv[2][jj], vv[3][jj]};
      *(bf16x4*)&Vt[(dofs + jj) * VST + kb] = pk;
    }
  };

  issue(0);
  commit();
  __syncthreads();

  for (int j = 0; j <= tq; ++j) {
    if (j < tq) issue(j + 1);  // in flight under this whole iteration

    // ---- S strip: 16 q-rows x 64 keys per wave ----
    float s[4][4];  // S[qrow=wave*16+quad*4+r][key=nt*16+col]
#pragma unroll
    for (int nt = 0; nt < 4; ++nt) {
      f32x4 acc = (f32x4){0.f, 0.f, 0.f, 0.f};
#pragma unroll
      for (int ks = 0; ks < 4; ++ks) {
        bf16x8 kf = *(const bf16x8*)&Ks[(nt * 16 + col) * KST + ks * 32 + quad * 8];
        acc = __builtin_amdgcn_mfma_f32_16x16x32_bf16(qf[ks], kf, acc, 0, 0, 0);
      }
#pragma unroll
      for (int r = 0; r < 4; ++r) s[nt][r] = acc[r] * SCL;
    }

    // causal mask on diagonal tile (key base == q base)
    if (j == tq) {
#pragma unroll
      for (int nt = 0; nt < 4; ++nt) {
        int kc = nt * 16 + col;
#pragma unroll
        for (int r = 0; r < 4; ++r)
          if (kc > wave * 16 + quad * 4 + r) s[nt][r] = NEG_BIG;
      }
    }

    // ---- online softmax: max-reduce only; l kept as per-lane partial ----
    float mx[4];
#pragma unroll
    for (int r = 0; r < 4; ++r) {
      float m0 = fmaxf(fmaxf(s[0][r], s[1][r]), fmaxf(s[2][r], s[3][r]));
#pragma unroll
      for (int off = 1; off < 16; off <<= 1)
        m0 = fmaxf(m0, __shfl_xor(m0, off, 64));
      mx[r] = m0;  // uniform across the row's 16 lanes
    }
    // T13 defer-max: wave-uniform skip of the O-rescale while growth < THR
    float need = fmaxf(fmaxf(mx[0] - m_i[0], mx[1] - m_i[1]),
                       fmaxf(mx[2] - m_i[2], mx[3] - m_i[3]));
    if (__any(need > DEFER_THR)) {
#pragma unroll
      for (int r = 0; r < 4; ++r) {
        float mnew = fmaxf(m_i[r], mx[r]);
        float alpha = exp2f(m_i[r] - mnew);
        lp[r] *= alpha;
        m_i[r] = mnew;
#pragma unroll
        for (int dt = 0; dt < 8; ++dt) o[dt][r] *= alpha;
      }
    }

    float p[4][4];
#pragma unroll
    for (int r = 0; r < 4; ++r) {
      float rs = 0.f;
#pragma unroll
      for (int nt = 0; nt < 4; ++nt) {
        float pv = exp2f(s[nt][r] - m_i[r]);  // bounded by 2^THR
        p[nt][r] = pv;
        rs += pv;
      }
      lp[r] += rs;
    }

    // ---- P: C-layout -> A-layout via per-wave LDS round trip ----
    // Wave-local region: same-wave DS ops are in-order; lgkmcnt(0) replaces
    // the old __syncthreads() here (memory clobber orders the compiler).
    bf16* pw = &Ps[wave * 16 * PST];
#pragma unroll
    for (int nt = 0; nt < 4; ++nt)
#pragma unroll
      for (int r = 0; r < 4; ++r)
        pw[(quad * 4 + r) * PST + nt * 16 + col] = (bf16)p[nt][r];
    asm volatile("s_waitcnt lgkmcnt(0)" ::: "memory");

    bf16x8 pf[2];
#pragma unroll
    for (int ks = 0; ks < 2; ++ks)
      pf[ks] = *(const bf16x8*)&pw[col * PST + ks * 32 + quad * 8];

    // ---- O += P·V ----
#pragma unroll
    for (int dt = 0; dt < 8; ++dt) {
#pragma unroll
      for (int ks = 0; ks < 2; ++ks) {
        const bf16* vb = &Vt[(dt * 16 + col) * VST + ks * 32 + quad * 8];
        bf16x4 lo = *(const bf16x4*)vb;  // VST=68: rows 8B-aligned -> 2x b64
        bf16x4 hi = *(const bf16x4*)(vb + 4);
        bf16x8 vf = {lo[0], lo[1], lo[2], lo[3], hi[0], hi[1], hi[2], hi[3]};
        o[dt] = __builtin_amdgcn_mfma_f32_16x16x32_bf16(pf[ks], vf, o[dt], 0, 0, 0);
      }
    }

    // ---- commit prefetched tile j+1 (the only 2 barriers per iteration) ----
    if (j < tq) {
      __syncthreads();  // all waves done reading tile j
      commit();         // vmcnt waits land here, hidden under the iteration
      __syncthreads();  // tile j+1 visible
    }
  }

  // ---- epilogue: reduce partial l across the row's 16 lanes, O / l ----
#pragma unroll
  for (int r = 0; r < 4; ++r) {
    float l = lp[r];
#pragma unroll
    for (int off = 1; off < 16; off <<= 1)
      l += __shfl_xor(l, off, 64);
    float inv = 1.f / l;
    float* orow = oh + (size_t)(q0 + wave * 16 + quad * 4 + r) * D_;
#pragma unroll
    for (int dt = 0; dt < 8; ++dt)
      orow[dt * 16 + col] = o[dt][r] * inv;
  }
}

extern "C" void kernel_launch(void* const* d_in, const int* in_sizes, int n_in,
                              void* d_out, int out_size, void* d_ws, size_t ws_size,
                              hipStream_t stream) {
  const int QN = B_ * H_ * S_ * D_;
  int qi, ki, vi;
  if (in_sizes[0] == QN)      { qi = 0; ki = 1; vi = 2; }
  else if (in_sizes[1] == QN) { qi = 1; ki = 0; vi = 2; }
  else                        { qi = 2; ki = 0; vi = 1; }
  const float* q = (const float*)d_in[qi];
  const float* k = (const float*)d_in[ki];
  const float* v = (const float*)d_in[vi];
  float* out = (float*)d_out;
  fa_mfma<<<dim3(2048), dim3(256), 0, stream>>>(q, k, v, out);
}